// Round 6
// baseline (596.762 us; speedup 1.0000x reference)
//
#include <hip/hip_runtime.h>
#include <math.h>
#include <stdint.h>

#define T_   512
#define H_   1024
#define I_   512
#define E_   64
#define K_   6
#define G_   8
#define TG_  3
#define EB_  80      // 64 routed + 16 shared-expert (half x token-eighth) blocks

typedef _Float16 h8 __attribute__((ext_vector_type(8)));
typedef _Float16 h4v __attribute__((ext_vector_type(4)));
typedef float    f4 __attribute__((ext_vector_type(4)));

// compact weight arena offsets (bytes)
#define CW_WU   33554432u
#define CW_WD   67108864u
#define CW_SHG 100663296u
#define CW_SHU 101711872u
#define CW_SHD 102760448u
#define CW_END 103809024u

// ------- router + xh-prep + pseudo-init + wrow table (fused, verified) --
__global__ __launch_bounds__(64) void router_k(
    const float* __restrict__ x, const float* __restrict__ gw,
    int* __restrict__ cnt, int* __restrict__ tlist,
    float* __restrict__ wrow, _Float16* __restrict__ xh)
{
  const int t   = blockIdx.x;
  const int tid = threadIdx.x;
  __shared__ float sx[H_];
  __shared__ float sc[E_];

  for (int h4 = tid; h4 < H_/4; h4 += 64)
    ((float4*)sx)[h4] = ((const float4*)(x + (size_t)t*H_))[h4];
  __syncthreads();

  for (int h4 = tid; h4 < H_/4; h4 += 64) {
    float4 v = ((const float4*)sx)[h4];
    h4v o = { (_Float16)v.x, (_Float16)v.y, (_Float16)v.z, (_Float16)v.w };
    *(h4v*)(xh + (size_t)t*H_ + h4*4) = o;
  }
  if (t < 16) {
    int s  = t*64 + tid;                      // 0..1023
    int e  = 64 + (s >> 9);
    int tt = s & 511;
    tlist[e*T_ + tt] = (tt << 13) | (3072 + s);
    wrow[3072 + s] = 1.0f;
    if (s == 0) { cnt[64] = T_; cnt[65] = T_; }
  }

  const float* wr = gw + (size_t)tid * H_;
  float acc = 0.f;
  for (int h = 0; h < H_; h += 4) {
    float4 xv = *(const float4*)(sx + h);
    float4 wv = *(const float4*)(wr + h);
    acc = fmaf(xv.x, wv.x, acc); acc = fmaf(xv.y, wv.y, acc);
    acc = fmaf(xv.z, wv.z, acc); acc = fmaf(xv.w, wv.w, acc);
  }
  sc[tid] = 1.f / (1.f + expf(-acc));
  __syncthreads();

  if (tid == 0) {
    float gs[G_];
    #pragma unroll
    for (int g = 0; g < G_; g++) {
      float m = sc[g*8];
      #pragma unroll
      for (int j = 1; j < 8; j++) m = fmaxf(m, sc[g*8+j]);
      gs[g] = m;
    }
    unsigned gp = 0;
    for (int r = 0; r < TG_; r++) {
      int best = 0; float bv = -1e30f;
      for (int g = 0; g < G_; g++)
        if (!((gp >> g) & 1) && gs[g] > bv) { bv = gs[g]; best = g; }
      gp |= 1u << best;
    }
    int   eidx[K_]; float ew[K_];
    unsigned long long em = 0ull;
    float wsum = 0.f;
    for (int r = 0; r < K_; r++) {
      int best = 0; float bv = -1e30f;
      for (int e = 0; e < E_; e++) {
        if (!((gp >> (e >> 3)) & 1)) continue;
        if ((em >> e) & 1ull) continue;
        if (sc[e] > bv) { bv = sc[e]; best = e; }
      }
      em |= 1ull << best; eidx[r] = best; ew[r] = bv; wsum += bv;
    }
    const float inv = 2.5f / (wsum + 1e-20f);
    for (int r = 0; r < K_; r++) {
      int e = eidx[r];
      int pos = atomicAdd(&cnt[e], 1);
      tlist[e*T_ + pos] = (t << 13) | (t*K_ + r);   // row = t*6+rank
      wrow[t*K_ + r] = ew[r] * inv;
    }
  }
}

// ---------------- compact: int32 weights -> int8 arena ------------------
// Pure flat copy, 16 elems/thread (64B read, 16B write), full occupancy.
// Grid = 6488064/256 = 25344 blocks exactly.
__global__ __launch_bounds__(256) void compact_k(
    const int* __restrict__ wg, const int* __restrict__ wu,
    const int* __restrict__ wd, const int* __restrict__ shwg,
    const int* __restrict__ shwu, const int* __restrict__ shwd,
    signed char* __restrict__ cw)
{
  long m = (long)blockIdx.x*256 + threadIdx.x;   // 16-elem chunk id
  const int* src; signed char* dst; long lm;
  if      (m < 2097152) { src = wg;   dst = cw;          lm = m; }
  else if (m < 4194304) { src = wu;   dst = cw + CW_WU;  lm = m - 2097152; }
  else if (m < 6291456) { src = wd;   dst = cw + CW_WD;  lm = m - 4194304; }
  else if (m < 6356992) { src = shwg; dst = cw + CW_SHG; lm = m - 6291456; }
  else if (m < 6422528) { src = shwu; dst = cw + CW_SHU; lm = m - 6356992; }
  else                  { src = shwd; dst = cw + CW_SHD; lm = m - 6422528; }
  const int4* s = (const int4*)(src) + lm*4;
  int4 a = s[0], b = s[1], c = s[2], d = s[3];
  unsigned p0 = (a.x&255u) | ((a.y&255u)<<8) | ((a.z&255u)<<16) | ((a.w&255u)<<24);
  unsigned p1 = (b.x&255u) | ((b.y&255u)<<8) | ((b.z&255u)<<16) | ((b.w&255u)<<24);
  unsigned p2 = (c.x&255u) | ((c.y&255u)<<8) | ((c.z&255u)<<16) | ((c.w&255u)<<24);
  unsigned p3 = (d.x&255u) | ((d.y&255u)<<8) | ((d.z&255u)<<16) | ((d.w&255u)<<24);
  int4 o = { (int)p0, (int)p1, (int)p2, (int)p3 };
  *(int4*)(dst + lm*16) = o;
}

// ---- expert-block descriptor: eb<64 -> routed; eb>=64 -> shared slice ---
__device__ __forceinline__ void eb_decode(int eb, const int* cnt,
                                          int& e, int& lo, int& hi) {
  if (eb < E_) { e = eb; lo = 0; hi = cnt[e]; }
  else { int q = (eb - E_) & 7; e = E_ + ((eb - E_) >> 3); lo = q*64; hi = lo + 64; }
}

// 8 int8 weights packed in int2 -> f16 fragment with scale folded
__device__ __forceinline__ h8 cvt8b(int2 w, float s) {
  union { _Float16 f[8]; h8 v; } t;
  t.f[0]=(_Float16)((float)((w.x<<24)>>24)*s);
  t.f[1]=(_Float16)((float)((w.x<<16)>>24)*s);
  t.f[2]=(_Float16)((float)((w.x<< 8)>>24)*s);
  t.f[3]=(_Float16)((float)( w.x     >>24)*s);
  t.f[4]=(_Float16)((float)((w.y<<24)>>24)*s);
  t.f[5]=(_Float16)((float)((w.y<<16)>>24)*s);
  t.f[6]=(_Float16)((float)((w.y<< 8)>>24)*s);
  t.f[7]=(_Float16)((float)( w.y     >>24)*s);
  return t.v;
}

// ---------------- gate+up MFMA: hmid[row, ic*64..+64) -------------------
// r4-proven structure, int8 weights (1/4 the staging bytes). 512 thr
// (8 waves = 4 tok-subtiles x 2 i-halves), grid 8x80, tile 64tok x 64i x
// {g,u}, K=1024, BK=32 -> 32 steps. Per step per thread: 1x int2 W-load
// (8B) + 1x h8 A-load; 3-deep W ring, 4-deep A ring; steady vmcnt(3)
// (positional: 1W+1A per step), tail 1/0; 1 barrier/step.
#define NKT_G 32

#define GU_STEP(KT, WN)                                                       \
  do {                                                                        \
    asm volatile("s_waitcnt vmcnt(" #WN ") lgkmcnt(0)" ::: "memory");         \
    __builtin_amdgcn_sched_barrier(0);                                        \
    __builtin_amdgcn_s_barrier();                                             \
    __builtin_amdgcn_sched_barrier(0);                                        \
    if ((KT) + 1 < NKT_G)                                                     \
      *(h8*)(wdst + (((KT)+1)&1)*5120) =                                      \
          cvt8b(Wr[((KT)+1)%3], sv[((KT)+1)>>2]);                             \
    if ((KT) + 3 < NKT_G)                                                     \
      Wr[((KT)+3)%3] = *(const int2*)(wsrc + ((KT)+3)*32);                    \
    {                                                                         \
      const _Float16* tb = lds0 + ((KT)&1)*5120;                              \
      h8 bg0 = *(const h8*)(tb + ro0);                                        \
      h8 bg1 = *(const h8*)(tb + ro1);                                        \
      h8 bu0 = *(const h8*)(tb + 2560 + ro0);                                 \
      h8 bu1 = *(const h8*)(tb + 2560 + ro1);                                 \
      accg0 = __builtin_amdgcn_mfma_f32_16x16x32_f16(Ar[(KT)%4], bg0, accg0, 0,0,0); \
      accg1 = __builtin_amdgcn_mfma_f32_16x16x32_f16(Ar[(KT)%4], bg1, accg1, 0,0,0); \
      accu0 = __builtin_amdgcn_mfma_f32_16x16x32_f16(Ar[(KT)%4], bu0, accu0, 0,0,0); \
      accu1 = __builtin_amdgcn_mfma_f32_16x16x32_f16(Ar[(KT)%4], bu1, accu1, 0,0,0); \
    }                                                                         \
    if ((KT) + 3 < NKT_G)                                                     \
      Ar[((KT)+3)%4] = *(const h8*)(ax + ((KT)+3)*32);                        \
  } while (0)

__global__ __launch_bounds__(512, 8) void gateup_k(
    const _Float16* __restrict__ xh, const signed char* __restrict__ cw,
    const float* __restrict__ sg, const float* __restrict__ su,
    const float* __restrict__ shsg, const float* __restrict__ shsu,
    const int* __restrict__ cnt, const int* __restrict__ tlist,
    const float* __restrict__ wrow,
    _Float16* __restrict__ hmid)
{
  const int ic = blockIdx.x;                  // i-chunk of 64 (0..7)
  const int eb = blockIdx.y;
  int e, lo, hi;
  eb_decode(eb, cnt, e, lo, hi);
  if (hi <= lo) return;

  const int tid  = threadIdx.x;
  const int lane = tid & 63;
  const int wv   = tid >> 6;                  // 0..7
  const int mr   = lane & 15;
  const int quad = lane >> 4;
  const int wm   = wv & 3;                    // token subtile
  const int wn   = wv >> 2;                   // i half (32 cols)

  const signed char *wgb, *wub; const float *sgp, *sup; int sib;
  if (e < E_) {
    wgb = cw + (size_t)e*I_*H_;
    wub = cw + CW_WU + (size_t)e*I_*H_;
    sgp = sg + e*32;  sup = su + e*32;  sib = ic >> 1;
  } else {
    int hf = e - E_;
    wgb = cw + CW_SHG + (size_t)hf*512*H_;
    wub = cw + CW_SHU + (size_t)hf*512*H_;
    sgp = shsg;  sup = shsu;  sib = hf*4 + (ic >> 1);
  }

  // staging role: threads 0..255 stage gate, 256..511 stage up
  const int smat = tid >> 8;
  const int sr   = (tid >> 2) & 63;           // tile row
  const int sseg = tid & 3;                   // 8-byte segment of 32-B step
  const signed char* wsrc = (smat ? wub : wgb) + (size_t)(ic*64 + sr)*H_ + sseg*8;
  const float* ssc = (smat ? sup : sgp) + sib*8;
  float sv[8];
  #pragma unroll
  for (int b = 0; b < 8; b++) sv[b] = ssc[b];

  __shared__ _Float16 wlds[2*2*64*40];        // dbuf x {g,u} x [64][40]
  __shared__ int stok[64]; __shared__ int srw[64]; __shared__ float swt[64];
  _Float16* lds0 = wlds;
  _Float16* wdst = wlds + smat*2560 + sr*40 + sseg*8;
  const int ro0 = (wn*32 + mr)*40 + quad*8;
  const int ro1 = ro0 + 16*40;

  int2 Wr[3];
  h8   Ar[4];

  for (int base = lo; base < hi; base += 64) {
    __syncthreads();
    if (tid < 64) {
      int slot = base + tid;
      if (slot < hi) {
        int ent = tlist[e*T_ + slot];
        stok[tid] = ent >> 13; srw[tid] = ent & 8191;
        swt[tid]  = wrow[ent & 8191];
      } else { stok[tid] = -1; srw[tid] = 0; swt[tid] = 0.f; }
    }
    __syncthreads();

    int tk = stok[wm*16 + mr]; if (tk < 0) tk = 0;
    const _Float16* ax = xh + (size_t)tk*H_ + quad*8;

    f4 accg0 = (f4){0.f,0.f,0.f,0.f}, accg1 = accg0, accu0 = accg0, accu1 = accg0;

    // prologue: W0 A0 W1 A1 W2 A2 (6 loads), wait W0 (pos1 -> vmcnt(5))
    Wr[0] = *(const int2*)(wsrc);        Ar[0] = *(const h8*)(ax);
    Wr[1] = *(const int2*)(wsrc + 32);   Ar[1] = *(const h8*)(ax + 32);
    Wr[2] = *(const int2*)(wsrc + 64);   Ar[2] = *(const h8*)(ax + 64);
    asm volatile("s_waitcnt vmcnt(5)" ::: "memory");
    __builtin_amdgcn_sched_barrier(0);
    *(h8*)(wdst) = cvt8b(Wr[0], sv[0]);

    GU_STEP(0,3);  GU_STEP(1,3);  GU_STEP(2,3);  GU_STEP(3,3);
    GU_STEP(4,3);  GU_STEP(5,3);  GU_STEP(6,3);  GU_STEP(7,3);
    GU_STEP(8,3);  GU_STEP(9,3);  GU_STEP(10,3); GU_STEP(11,3);
    GU_STEP(12,3); GU_STEP(13,3); GU_STEP(14,3); GU_STEP(15,3);
    GU_STEP(16,3); GU_STEP(17,3); GU_STEP(18,3); GU_STEP(19,3);
    GU_STEP(20,3); GU_STEP(21,3); GU_STEP(22,3); GU_STEP(23,3);
    GU_STEP(24,3); GU_STEP(25,3); GU_STEP(26,3); GU_STEP(27,3);
    GU_STEP(28,3); GU_STEP(29,3); GU_STEP(30,1); GU_STEP(31,0);

    // epilogue: silu(g)*u*w -> hmid  (C/D: col=mr (i), row=quad*4+r (tok))
    const int icol = ic*64 + wn*32 + mr;
    #pragma unroll
    for (int r = 0; r < 4; r++) {
      int sl = wm*16 + quad*4 + r;
      if (stok[sl] >= 0) {
        float wt = swt[sl];
        float g0 = accg0[r];
        float m0 = g0 / (1.f + expf(-g0)) * accu0[r] * wt;
        float g1 = accg1[r];
        float m1 = g1 / (1.f + expf(-g1)) * accu1[r] * wt;
        _Float16* hp = hmid + (size_t)srw[sl]*I_ + icol;
        hp[0]  = (_Float16)m0;
        hp[16] = (_Float16)m1;
      }
    }
  }
}
#undef GU_STEP

// ---------------- down MFMA: scr[t*8+rank, hc*64..+64) = hmid @ Wd ------
// r4-proven transpose-stage structure, int8 Wd. 256 thr, grid 16x80,
// K=512, BK=32 -> 16 steps. Per step per thread: 4x ushort W-loads
// (2B, 4 i-rows x 2 h-cols) + 1 A-load -> 5 loads/step; steady vmcnt(6).
#define NKT_D 16

#define DN_LDW(S, KT)                                                         \
  do {                                                                        \
    Wr[S][0] = *(const unsigned short*)(dsrc + (size_t)((KT)*32 + 0)*H_);     \
    Wr[S][1] = *(const unsigned short*)(dsrc + (size_t)((KT)*32 + 1)*H_);     \
    Wr[S][2] = *(const unsigned short*)(dsrc + (size_t)((KT)*32 + 2)*H_);     \
    Wr[S][3] = *(const unsigned short*)(dsrc + (size_t)((KT)*32 + 3)*H_);     \
  } while (0)

#define DN_WRITE(S, BUF, SC)                                                  \
  do {                                                                        \
    union { _Float16 f[4]; h4v v; } v0, v1;                                   \
    v0.f[0]=(_Float16)((float)(signed char)(Wr[S][0]     )*(SC));             \
    v0.f[1]=(_Float16)((float)(signed char)(Wr[S][1]     )*(SC));             \
    v0.f[2]=(_Float16)((float)(signed char)(Wr[S][2]     )*(SC));             \
    v0.f[3]=(_Float16)((float)(signed char)(Wr[S][3]     )*(SC));             \
    v1.f[0]=(_Float16)((float)(signed char)(Wr[S][0] >> 8)*(SC));             \
    v1.f[1]=(_Float16)((float)(signed char)(Wr[S][1] >> 8)*(SC));             \
    v1.f[2]=(_Float16)((float)(signed char)(Wr[S][2] >> 8)*(SC));             \
    v1.f[3]=(_Float16)((float)(signed char)(Wr[S][3] >> 8)*(SC));             \
    *(h4v*)(ddst0 + (BUF)*2560)      = v0.v;                                  \
    *(h4v*)(ddst0 + (BUF)*2560 + 40) = v1.v;                                  \
  } while (0)

#define DN_STEP(KT, WN)                                                       \
  do {                                                                        \
    asm volatile("s_waitcnt vmcnt(" #WN ") lgkmcnt(0)" ::: "memory");         \
    __builtin_amdgcn_sched_barrier(0);                                        \
    __builtin_amdgcn_s_barrier();                                             \
    __builtin_amdgcn_sched_barrier(0);                                        \
    if ((KT) + 1 < NKT_D) DN_WRITE(((KT)+1)%3, ((KT)+1)&1, scd[((KT)+1)>>2]); \
    if ((KT) + 3 < NKT_D) DN_LDW(((KT)+3)%3, (KT)+3);                         \
    {                                                                         \
      const _Float16* tb = lds0 + ((KT)&1)*2560;                              \
      h8 b0 = *(const h8*)(tb + ro0);                                         \
      h8 b1 = *(const h8*)(tb + ro1);                                         \
      h8 b2 = *(const h8*)(tb + ro2);                                         \
      h8 b3 = *(const h8*)(tb + ro3);                                         \
      tot0 = __builtin_amdgcn_mfma_f32_16x16x32_f16(Ar[(KT)%4], b0, tot0, 0,0,0); \
      tot1 = __builtin_amdgcn_mfma_f32_16x16x32_f16(Ar[(KT)%4], b1, tot1, 0,0,0); \
      tot2 = __builtin_amdgcn_mfma_f32_16x16x32_f16(Ar[(KT)%4], b2, tot2, 0,0,0); \
      tot3 = __builtin_amdgcn_mfma_f32_16x16x32_f16(Ar[(KT)%4], b3, tot3, 0,0,0); \
    }                                                                         \
    if ((KT) + 3 < NKT_D)                                                     \
      Ar[((KT)+3)%4] = *(const h8*)(ap + ((KT)+3)*32);                        \
  } while (0)

__global__ __launch_bounds__(256, 6) void down_k(
    const signed char* __restrict__ cw,
    const float* __restrict__ sd, const float* __restrict__ shsd,
    const int* __restrict__ cnt, const int* __restrict__ tlist,
    const _Float16* __restrict__ hmid, float* __restrict__ scr)
{
  const int hc = blockIdx.x;                  // h-chunk of 64 (0..15)
  const int eb = blockIdx.y;
  int e, lo, hi;
  eb_decode(eb, cnt, e, lo, hi);
  if (hi <= lo) return;

  const int tid  = threadIdx.x;
  const int lane = tid & 63;
  const int wv   = tid >> 6;                  // token subtile
  const int mr   = lane & 15;
  const int quad = lane >> 4;

  const signed char* wb; const float* sdp; int sib0;
  if (e < E_) { wb = cw + CW_WD + (size_t)e*I_*H_; sdp = sd + e*32;  sib0 = 0; }
  else { int hf = e - E_; wb = cw + CW_SHD + (size_t)hf*512*H_; sdp = shsd; sib0 = hf*4; }
  float scd[4];
  #pragma unroll
  for (int ib = 0; ib < 4; ib++) scd[ib] = sdp[(sib0+ib)*8 + (hc >> 1)];

  // staging: ig = tid>>5 (4-row i group), hp = tid&31 (2 h-cols)
  const int ig = tid >> 5;
  const int hp = tid & 31;
  const signed char* dsrc = wb + (size_t)(ig*4)*H_ + hc*64 + hp*2;

  __shared__ _Float16 wlds[2*64*40];          // dbuf x [64 h][40]
  __shared__ int stok[64]; __shared__ int srw[64];
  _Float16* lds0  = wlds;
  _Float16* ddst0 = wlds + (hp*2)*40 + ig*4;
  const int ro0 = (     mr)*40 + quad*8;
  const int ro1 = (16 + mr)*40 + quad*8;
  const int ro2 = (32 + mr)*40 + quad*8;
  const int ro3 = (48 + mr)*40 + quad*8;

  unsigned short Wr[3][4];
  h8 Ar[4];

  for (int base = lo; base < hi; base += 64) {
    __syncthreads();
    if (tid < 64) {
      int slot = base + tid;
      if (slot < hi) {
        int ent = tlist[e*T_ + slot];
        stok[tid] = ent >> 13; srw[tid] = ent & 8191;
      } else { stok[tid] = -1; srw[tid] = 0; }
    }
    __syncthreads();

    const _Float16* ap = hmid + (size_t)srw[wv*16 + mr]*I_ + quad*8;

    f4 tot0 = (f4){0.f,0.f,0.f,0.f}, tot1 = tot0, tot2 = tot0, tot3 = tot0;

    // prologue: W0(4) A0 W1(4) A1 W2(4) A2 = 15 loads; wait W0+A0
    DN_LDW(0, 0); Ar[0] = *(const h8*)(ap);
    DN_LDW(1, 1); Ar[1] = *(const h8*)(ap + 32);
    DN_LDW(2, 2); Ar[2] = *(const h8*)(ap + 64);
    asm volatile("s_waitcnt vmcnt(10)" ::: "memory");
    __builtin_amdgcn_sched_barrier(0);
    DN_WRITE(0, 0, scd[0]);

    DN_STEP(0,6);  DN_STEP(1,6);  DN_STEP(2,6);  DN_STEP(3,6);
    DN_STEP(4,6);  DN_STEP(5,6);  DN_STEP(6,6);  DN_STEP(7,6);
    DN_STEP(8,6);  DN_STEP(9,6);  DN_STEP(10,6); DN_STEP(11,6);
    DN_STEP(12,6); DN_STEP(13,6); DN_STEP(14,1); DN_STEP(15,0);

    // epilogue: exactly-once stores to scr[(t*8+rank)][hcol]
    #pragma unroll
    for (int r = 0; r < 4; r++) {
      int sl = wv*16 + quad*4 + r;
      if (stok[sl] >= 0) {
        int t  = stok[sl];
        int sr = srw[sl];
        int rank = (sr < 3072) ? (sr - t*6) : (6 + ((sr - 3072) >> 9));
        float* dst = scr + (size_t)(t*8 + rank)*H_ + hc*64 + mr;
        dst[0]  = tot0[r];
        dst[16] = tot1[r];
        dst[32] = tot2[r];
        dst[48] = tot3[r];
      }
    }
  }
}
#undef DN_STEP
#undef DN_WRITE
#undef DN_LDW

// ---------------- combine: out[t,h] = sum_r scr[t*8+r, h] ---------------
__global__ __launch_bounds__(256) void combine_k(
    const float* __restrict__ scr, float* __restrict__ out)
{
  int i = blockIdx.x*256 + threadIdx.x;       // float4 index over T*H/4
  int t = i >> 8;
  int c = i & 255;
  const float4* base = (const float4*)(scr + (size_t)t*8*H_) + c;
  float4 s = base[0];
  #pragma unroll
  for (int r = 1; r < 8; r++) {
    float4 v = base[(size_t)r*(H_/4)];
    s.x += v.x; s.y += v.y; s.z += v.z; s.w += v.w;
  }
  ((float4*)out)[i] = s;
}

// ---------------- launch ----------------
extern "C" void kernel_launch(void* const* d_in, const int* in_sizes, int n_in,
                              void* d_out, int out_size, void* d_ws, size_t ws_size,
                              hipStream_t stream) {
  (void)in_sizes; (void)n_in; (void)ws_size; (void)out_size;
  const float* x    = (const float*)d_in[0];
  const float* gw   = (const float*)d_in[1];
  const int*   wg   = (const int*  )d_in[2];
  const float* sg   = (const float*)d_in[3];
  const int*   wu   = (const int*  )d_in[4];
  const float* su   = (const float*)d_in[5];
  const int*   wd   = (const int*  )d_in[6];
  const float* sd   = (const float*)d_in[7];
  const int*   shwg = (const int*  )d_in[8];
  const float* shsg = (const float*)d_in[9];
  const int*   shwu = (const int*  )d_in[10];
  const float* shsu = (const float*)d_in[11];
  const int*   shwd = (const int*  )d_in[12];
  const float* shsd = (const float*)d_in[13];
  float* out = (float*)d_out;

  char* ws = (char*)d_ws;
  int*         cnt   = (int*        ) ws;                   // 1 KB
  int*         tlist = (int*        )(ws + 1024);           // 132 KB
  float*       wrow  = (float*      )(ws + 136192);         // 16 KB
  _Float16*    hmid  = (_Float16*   )(ws + 152576);         // 4 MB
  _Float16*    xh    = (_Float16*   )(ws + 4346880);        // 1 MB
  float*       scr   = (float*      )(ws + 5395456);        // 16 MB
  signed char* cw    = (signed char*)(ws + 22172672);       // 104 MB -> ~126 MB total

  hipMemsetAsync(cnt, 0, 1024, stream);
  compact_k<<<25344, 256, 0, stream>>>(wg, wu, wd, shwg, shwu, shwd, cw);
  router_k<<<T_, 64, 0, stream>>>(x, gw, cnt, tlist, wrow, xh);
  gateup_k<<<dim3(8, EB_), 512, 0, stream>>>(xh, cw, sg, su, shsg, shsu,
                                             cnt, tlist, wrow, hmid);
  down_k<<<dim3(16, EB_), 256, 0, stream>>>(cw, sd, shsd,
                                            cnt, tlist, hmid, scr);
  combine_k<<<512, 256, 0, stream>>>(scr, out);
}

// Round 7
// 539.690 us; speedup vs baseline: 1.1057x; 1.1057x over previous
//
#include <hip/hip_runtime.h>
#include <math.h>
#include <stdint.h>

#define T_   512
#define H_   1024
#define I_   512
#define E_   64
#define K_   6
#define G_   8
#define TG_  3
#define EB_  80      // 64 routed + 16 shared-expert (half x token-eighth) blocks

typedef _Float16 h8 __attribute__((ext_vector_type(8)));
typedef _Float16 h4v __attribute__((ext_vector_type(4)));
typedef _Float16 h2v __attribute__((ext_vector_type(2)));
typedef float    f4 __attribute__((ext_vector_type(4)));

// ------- router + xh-prep + pseudo-init + wrow table (fused, verified) --
__global__ __launch_bounds__(64) void router_k(
    const float* __restrict__ x, const float* __restrict__ gw,
    int* __restrict__ cnt, int* __restrict__ tlist,
    float* __restrict__ wrow, _Float16* __restrict__ xh)
{
  const int t   = blockIdx.x;
  const int tid = threadIdx.x;
  __shared__ float sx[H_];
  __shared__ float sc[E_];

  for (int h4 = tid; h4 < H_/4; h4 += 64)
    ((float4*)sx)[h4] = ((const float4*)(x + (size_t)t*H_))[h4];
  __syncthreads();

  for (int h4 = tid; h4 < H_/4; h4 += 64) {
    float4 v = ((const float4*)sx)[h4];
    h4v o = { (_Float16)v.x, (_Float16)v.y, (_Float16)v.z, (_Float16)v.w };
    *(h4v*)(xh + (size_t)t*H_ + h4*4) = o;
  }
  if (t < 16) {
    int s  = t*64 + tid;                      // 0..1023
    int e  = 64 + (s >> 9);
    int tt = s & 511;
    tlist[e*T_ + tt] = (tt << 13) | (3072 + s);
    wrow[3072 + s] = 1.0f;
    if (s == 0) { cnt[64] = T_; cnt[65] = T_; }
  }

  const float* wr = gw + (size_t)tid * H_;
  float acc = 0.f;
  for (int h = 0; h < H_; h += 4) {
    float4 xv = *(const float4*)(sx + h);
    float4 wv = *(const float4*)(wr + h);
    acc = fmaf(xv.x, wv.x, acc); acc = fmaf(xv.y, wv.y, acc);
    acc = fmaf(xv.z, wv.z, acc); acc = fmaf(xv.w, wv.w, acc);
  }
  sc[tid] = 1.f / (1.f + expf(-acc));
  __syncthreads();

  if (tid == 0) {
    float gs[G_];
    #pragma unroll
    for (int g = 0; g < G_; g++) {
      float m = sc[g*8];
      #pragma unroll
      for (int j = 1; j < 8; j++) m = fmaxf(m, sc[g*8+j]);
      gs[g] = m;
    }
    unsigned gp = 0;
    for (int r = 0; r < TG_; r++) {
      int best = 0; float bv = -1e30f;
      for (int g = 0; g < G_; g++)
        if (!((gp >> g) & 1) && gs[g] > bv) { bv = gs[g]; best = g; }
      gp |= 1u << best;
    }
    int   eidx[K_]; float ew[K_];
    unsigned long long em = 0ull;
    float wsum = 0.f;
    for (int r = 0; r < K_; r++) {
      int best = 0; float bv = -1e30f;
      for (int e = 0; e < E_; e++) {
        if (!((gp >> (e >> 3)) & 1)) continue;
        if ((em >> e) & 1ull) continue;
        if (sc[e] > bv) { bv = sc[e]; best = e; }
      }
      em |= 1ull << best; eidx[r] = best; ew[r] = bv; wsum += bv;
    }
    const float inv = 2.5f / (wsum + 1e-20f);
    for (int r = 0; r < K_; r++) {
      int e = eidx[r];
      int pos = atomicAdd(&cnt[e], 1);
      tlist[e*T_ + pos] = (t << 13) | (t*K_ + r);   // row = t*6+rank
      wrow[t*K_ + r] = ew[r] * inv;
    }
  }
}

// ---- expert-block descriptor: eb<64 -> routed; eb>=64 -> shared slice ---
__device__ __forceinline__ void eb_decode(int eb, const int* cnt,
                                          int& e, int& lo, int& hi) {
  if (eb < E_) { e = eb; lo = 0; hi = cnt[e]; }
  else { int q = (eb - E_) & 7; e = E_ + ((eb - E_) >> 3); lo = q*64; hi = lo + 64; }
}

// int4 (4 int32 weights) -> 4x f16 with scale folded
__device__ __forceinline__ h4v cvt4i(int4 w, float s) {
  h4v t = { (_Float16)((float)w.x*s), (_Float16)((float)w.y*s),
            (_Float16)((float)w.z*s), (_Float16)((float)w.w*s) };
  return t;
}

// ---------------- gate+up MFMA: hmid[row, bi*32..+32) -------------------
// Occupancy-first, clean-traffic: 32-i tiles, grid 16x80 = 1280 blocks x
// 8 waves = 40 waves/CU available; launch_bounds(512,8) caps 32/CU
// (4 blocks, 10KB LDS each). Waves: wm=wv&3 (16-tok subtile), wn=wv>>2
// (16-i half). Per thread per step: 1 int4 W-load + 1 h8 A-load; 3-deep
// W ring, 4-deep A ring; steady vmcnt(3), tail 1/0 (same arithmetic as
// r6's verified skeleton); 1 barrier/step; weights read exactly once.
#define NKT_G 32

#define GU_STEP(KT, WN)                                                       \
  do {                                                                        \
    asm volatile("s_waitcnt vmcnt(" #WN ") lgkmcnt(0)" ::: "memory");         \
    __builtin_amdgcn_sched_barrier(0);                                        \
    __builtin_amdgcn_s_barrier();                                             \
    __builtin_amdgcn_sched_barrier(0);                                        \
    if ((KT) + 1 < NKT_G)                                                     \
      *(h4v*)(wdst + (((KT)+1)&1)*2560) =                                     \
          cvt4i(Wr[((KT)+1)%3], sv[((KT)+1)>>2]);                             \
    if ((KT) + 3 < NKT_G)                                                     \
      Wr[((KT)+3)%3] = *(const int4*)(wsrc + ((KT)+3)*32);                    \
    {                                                                         \
      const _Float16* tb = lds0 + ((KT)&1)*2560;                              \
      h8 bg = *(const h8*)(tb + ro0);                                         \
      h8 bu = *(const h8*)(tb + 1280 + ro0);                                  \
      accg = __builtin_amdgcn_mfma_f32_16x16x32_f16(Ar[(KT)%4], bg, accg, 0,0,0); \
      accu = __builtin_amdgcn_mfma_f32_16x16x32_f16(Ar[(KT)%4], bu, accu, 0,0,0); \
    }                                                                         \
    if ((KT) + 3 < NKT_G)                                                     \
      Ar[((KT)+3)%4] = *(const h8*)(ax + ((KT)+3)*32);                        \
  } while (0)

__global__ __launch_bounds__(512, 8) void gateup_k(
    const _Float16* __restrict__ xh,
    const int* __restrict__ wg, const float* __restrict__ sg,
    const int* __restrict__ wu, const float* __restrict__ su,
    const int* __restrict__ shwg, const float* __restrict__ shsg,
    const int* __restrict__ shwu, const float* __restrict__ shsu,
    const int* __restrict__ cnt, const int* __restrict__ tlist,
    const float* __restrict__ wrow,
    _Float16* __restrict__ hmid)
{
  const int bi = blockIdx.x;                  // i-chunk of 32 (0..15)
  const int eb = blockIdx.y;
  int e, lo, hi;
  eb_decode(eb, cnt, e, lo, hi);
  if (hi <= lo) return;

  const int tid  = threadIdx.x;
  const int lane = tid & 63;
  const int wv   = tid >> 6;                  // 0..7
  const int mr   = lane & 15;
  const int quad = lane >> 4;
  const int wm   = wv & 3;                    // token subtile (16 tok)
  const int wn   = wv >> 2;                   // i half (16 cols)

  const int *wgb, *wub; const float *sgp, *sup; int sib;
  if (e < E_) {
    wgb = wg + (size_t)e*I_*H_;  wub = wu + (size_t)e*I_*H_;
    sgp = sg + e*32;  sup = su + e*32;  sib = bi >> 2;
  } else {
    int hf = e - E_;
    wgb = shwg + (size_t)hf*512*H_;  wub = shwu + (size_t)hf*512*H_;
    sgp = shsg;  sup = shsu;  sib = hf*4 + (bi >> 2);
  }

  // staging role: threads 0..255 stage gate, 256..511 stage up
  const int smat = tid >> 8;
  const int sr   = (tid >> 3) & 31;           // tile row (i)
  const int seg  = tid & 7;                   // 4-int segment of 32-int step
  const int* wsrc = (smat ? wub : wgb) + (size_t)(bi*32 + sr)*H_ + seg*4;
  const float* ssc = (smat ? sup : sgp) + sib*8;
  float sv[8];
  #pragma unroll
  for (int b = 0; b < 8; b++) sv[b] = ssc[b];

  __shared__ _Float16 wlds[2*2*32*40];        // [buf][mat][row][40] 10KB
  __shared__ int stok[64]; __shared__ int srw[64]; __shared__ float swt[64];
  _Float16* lds0 = wlds;
  _Float16* wdst = wlds + smat*1280 + sr*40 + seg*4;
  const int ro0 = (wn*16 + mr)*40 + quad*8;

  int4 Wr[3];
  h8   Ar[4];

  for (int base = lo; base < hi; base += 64) {
    __syncthreads();
    if (tid < 64) {
      int slot = base + tid;
      if (slot < hi) {
        int ent = tlist[e*T_ + slot];
        stok[tid] = ent >> 13; srw[tid] = ent & 8191;
        swt[tid]  = wrow[ent & 8191];
      } else { stok[tid] = -1; srw[tid] = 0; swt[tid] = 0.f; }
    }
    __syncthreads();

    int tk = stok[wm*16 + mr]; if (tk < 0) tk = 0;
    const _Float16* ax = xh + (size_t)tk*H_ + quad*8;

    f4 accg = (f4){0.f,0.f,0.f,0.f}, accu = accg;

    // prologue: W0 A0 W1 A1 W2 A2 (6 loads), wait W0 -> vmcnt(5)
    Wr[0] = *(const int4*)(wsrc);        Ar[0] = *(const h8*)(ax);
    Wr[1] = *(const int4*)(wsrc + 32);   Ar[1] = *(const h8*)(ax + 32);
    Wr[2] = *(const int4*)(wsrc + 64);   Ar[2] = *(const h8*)(ax + 64);
    asm volatile("s_waitcnt vmcnt(5)" ::: "memory");
    __builtin_amdgcn_sched_barrier(0);
    *(h4v*)(wdst) = cvt4i(Wr[0], sv[0]);

    GU_STEP(0,3);  GU_STEP(1,3);  GU_STEP(2,3);  GU_STEP(3,3);
    GU_STEP(4,3);  GU_STEP(5,3);  GU_STEP(6,3);  GU_STEP(7,3);
    GU_STEP(8,3);  GU_STEP(9,3);  GU_STEP(10,3); GU_STEP(11,3);
    GU_STEP(12,3); GU_STEP(13,3); GU_STEP(14,3); GU_STEP(15,3);
    GU_STEP(16,3); GU_STEP(17,3); GU_STEP(18,3); GU_STEP(19,3);
    GU_STEP(20,3); GU_STEP(21,3); GU_STEP(22,3); GU_STEP(23,3);
    GU_STEP(24,3); GU_STEP(25,3); GU_STEP(26,3); GU_STEP(27,3);
    GU_STEP(28,3); GU_STEP(29,3); GU_STEP(30,1); GU_STEP(31,0);

    // epilogue: silu(g)*u*w -> hmid  (C/D: col=mr (i), row=quad*4+r (tok))
    const int icol = bi*32 + wn*16 + mr;
    #pragma unroll
    for (int r = 0; r < 4; r++) {
      int sl = wm*16 + quad*4 + r;
      if (stok[sl] >= 0) {
        float wt = swt[sl];
        float g0 = accg[r];
        float m0 = g0 / (1.f + expf(-g0)) * accu[r] * wt;
        hmid[(size_t)srw[sl]*I_ + icol] = (_Float16)m0;
      }
    }
  }
}
#undef GU_STEP

// ---------------- down MFMA: scr[t*8+rank, hc*32..+32) = hmid @ Wd ------
// 32-h tiles: grid 32x80 = 2560 blocks x 4 waves = 40 waves/CU available;
// launch_bounds(256,8) caps 32/CU (8 blocks, 5KB LDS each). Per thread per
// step: 2 int2 W-loads (2 i-rows x 2 h-cols, transposed into LDS) + 1 A.
// Steady vmcnt(4) (retire A(kt)+W(kt+1)x2), tail 1/0; prologue vmcnt(7).
#define NKT_D 16

#define DN_LDW(S, KT)                                                         \
  do {                                                                        \
    Wr[S][0] = *(const int2*)(dsrc + (size_t)((KT)*32 + 0)*H_);               \
    Wr[S][1] = *(const int2*)(dsrc + (size_t)((KT)*32 + 1)*H_);               \
  } while (0)

#define DN_WRITE(S, BUF, SC)                                                  \
  do {                                                                        \
    h2v v0 = { (_Float16)((float)Wr[S][0].x*(SC)),                            \
               (_Float16)((float)Wr[S][1].x*(SC)) };                          \
    h2v v1 = { (_Float16)((float)Wr[S][0].y*(SC)),                            \
               (_Float16)((float)Wr[S][1].y*(SC)) };                          \
    *(h2v*)(ddst0 + (BUF)*1280)      = v0;                                    \
    *(h2v*)(ddst0 + (BUF)*1280 + 40) = v1;                                    \
  } while (0)

#define DN_STEP(KT, WN)                                                       \
  do {                                                                        \
    asm volatile("s_waitcnt vmcnt(" #WN ") lgkmcnt(0)" ::: "memory");         \
    __builtin_amdgcn_sched_barrier(0);                                        \
    __builtin_amdgcn_s_barrier();                                             \
    __builtin_amdgcn_sched_barrier(0);                                        \
    if ((KT) + 1 < NKT_D) DN_WRITE(((KT)+1)%3, ((KT)+1)&1, scd[((KT)+1)>>2]); \
    if ((KT) + 3 < NKT_D) DN_LDW(((KT)+3)%3, (KT)+3);                         \
    {                                                                         \
      const _Float16* tb = lds0 + ((KT)&1)*1280;                              \
      h8 b0 = *(const h8*)(tb + ro0);                                         \
      h8 b1 = *(const h8*)(tb + ro1);                                         \
      tot0 = __builtin_amdgcn_mfma_f32_16x16x32_f16(Ar[(KT)%4], b0, tot0, 0,0,0); \
      tot1 = __builtin_amdgcn_mfma_f32_16x16x32_f16(Ar[(KT)%4], b1, tot1, 0,0,0); \
    }                                                                         \
    if ((KT) + 3 < NKT_D)                                                     \
      Ar[((KT)+3)%4] = *(const h8*)(ap + ((KT)+3)*32);                        \
  } while (0)

__global__ __launch_bounds__(256, 8) void down_k(
    const int* __restrict__ wd, const float* __restrict__ sd,
    const int* __restrict__ shwd, const float* __restrict__ shsd,
    const int* __restrict__ cnt, const int* __restrict__ tlist,
    const _Float16* __restrict__ hmid, float* __restrict__ scr)
{
  const int hc = blockIdx.x;                  // h-chunk of 32 (0..31)
  const int eb = blockIdx.y;
  int e, lo, hi;
  eb_decode(eb, cnt, e, lo, hi);
  if (hi <= lo) return;

  const int tid  = threadIdx.x;
  const int lane = tid & 63;
  const int wv   = tid >> 6;                  // token subtile (16 tok)
  const int mr   = lane & 15;
  const int quad = lane >> 4;

  const int* wb; const float* sdp; int sib0;
  if (e < E_) { wb = wd + (size_t)e*I_*H_;        sdp = sd + e*32;  sib0 = 0; }
  else { int hf = e - E_; wb = shwd + (size_t)hf*512*H_; sdp = shsd; sib0 = hf*4; }
  float scd[4];
  #pragma unroll
  for (int ib = 0; ib < 4; ib++) scd[ib] = sdp[(sib0+ib)*8 + (hc >> 2)];

  // staging: ig = tid>>4 (2-row i group), hp = tid&15 (2 h-cols)
  const int ig = tid >> 4;
  const int hp = tid & 15;
  const int* dsrc = wb + (size_t)(ig*2)*H_ + hc*32 + hp*2;

  __shared__ _Float16 wlds[2*32*40];          // [buf][h][40] 5KB
  __shared__ int stok[64]; __shared__ int srw[64];
  _Float16* lds0  = wlds;
  _Float16* ddst0 = wlds + (hp*2)*40 + ig*2;
  const int ro0 = (     mr)*40 + quad*8;
  const int ro1 = (16 + mr)*40 + quad*8;

  int2 Wr[3][2];
  h8   Ar[4];

  for (int base = lo; base < hi; base += 64) {
    __syncthreads();
    if (tid < 64) {
      int slot = base + tid;
      if (slot < hi) {
        int ent = tlist[e*T_ + slot];
        stok[tid] = ent >> 13; srw[tid] = ent & 8191;
      } else { stok[tid] = -1; srw[tid] = 0; }
    }
    __syncthreads();

    const _Float16* ap = hmid + (size_t)srw[wv*16 + mr]*I_ + quad*8;

    f4 tot0 = (f4){0.f,0.f,0.f,0.f}, tot1 = tot0;

    // prologue: W0(2) A0 W1(2) A1 W2(2) A2 = 9 loads; wait W0 -> vmcnt(7)
    DN_LDW(0, 0); Ar[0] = *(const h8*)(ap);
    DN_LDW(1, 1); Ar[1] = *(const h8*)(ap + 32);
    DN_LDW(2, 2); Ar[2] = *(const h8*)(ap + 64);
    asm volatile("s_waitcnt vmcnt(7)" ::: "memory");
    __builtin_amdgcn_sched_barrier(0);
    DN_WRITE(0, 0, scd[0]);

    DN_STEP(0,4);  DN_STEP(1,4);  DN_STEP(2,4);  DN_STEP(3,4);
    DN_STEP(4,4);  DN_STEP(5,4);  DN_STEP(6,4);  DN_STEP(7,4);
    DN_STEP(8,4);  DN_STEP(9,4);  DN_STEP(10,4); DN_STEP(11,4);
    DN_STEP(12,4); DN_STEP(13,4); DN_STEP(14,1); DN_STEP(15,0);

    // epilogue: exactly-once stores to scr[(t*8+rank)][hcol]
    #pragma unroll
    for (int r = 0; r < 4; r++) {
      int sl = wv*16 + quad*4 + r;
      if (stok[sl] >= 0) {
        int t  = stok[sl];
        int sr = srw[sl];
        int rank = (sr < 3072) ? (sr - t*6) : (6 + ((sr - 3072) >> 9));
        float* dst = scr + (size_t)(t*8 + rank)*H_ + hc*32 + mr;
        dst[0]  = tot0[r];
        dst[16] = tot1[r];
      }
    }
  }
}
#undef DN_STEP
#undef DN_WRITE
#undef DN_LDW

// ---------------- combine: out[t,h] = sum_r scr[t*8+r, h] ---------------
__global__ __launch_bounds__(256) void combine_k(
    const float* __restrict__ scr, float* __restrict__ out)
{
  int i = blockIdx.x*256 + threadIdx.x;       // float4 index over T*H/4
  int t = i >> 8;
  int c = i & 255;
  const float4* base = (const float4*)(scr + (size_t)t*8*H_) + c;
  float4 s = base[0];
  #pragma unroll
  for (int r = 1; r < 8; r++) {
    float4 v = base[(size_t)r*(H_/4)];
    s.x += v.x; s.y += v.y; s.z += v.z; s.w += v.w;
  }
  ((float4*)out)[i] = s;
}

// ---------------- launch ----------------
extern "C" void kernel_launch(void* const* d_in, const int* in_sizes, int n_in,
                              void* d_out, int out_size, void* d_ws, size_t ws_size,
                              hipStream_t stream) {
  (void)in_sizes; (void)n_in; (void)ws_size; (void)out_size;
  const float* x    = (const float*)d_in[0];
  const float* gw   = (const float*)d_in[1];
  const int*   wg   = (const int*  )d_in[2];
  const float* sg   = (const float*)d_in[3];
  const int*   wu   = (const int*  )d_in[4];
  const float* su   = (const float*)d_in[5];
  const int*   wd   = (const int*  )d_in[6];
  const float* sd   = (const float*)d_in[7];
  const int*   shwg = (const int*  )d_in[8];
  const float* shsg = (const float*)d_in[9];
  const int*   shwu = (const int*  )d_in[10];
  const float* shsu = (const float*)d_in[11];
  const int*   shwd = (const int*  )d_in[12];
  const float* shsd = (const float*)d_in[13];
  float* out = (float*)d_out;

  char* ws = (char*)d_ws;
  int*      cnt   = (int*     ) ws;                       // 1 KB
  int*      tlist = (int*     )(ws + 1024);               // 132 KB
  float*    wrow  = (float*   )(ws + 136192);             // 16 KB
  _Float16* hmid  = (_Float16*)(ws + 152576);             // 4 MB
  _Float16* xh    = (_Float16*)(ws + 4346880);            // 1 MB
  float*    scr   = (float*   )(ws + 5395456);            // 16 MB

  hipMemsetAsync(cnt, 0, 1024, stream);
  router_k<<<T_, 64, 0, stream>>>(x, gw, cnt, tlist, wrow, xh);
  gateup_k<<<dim3(16, EB_), 512, 0, stream>>>(xh, wg, sg, wu, su,
                                              shwg, shsg, shwu, shsu,
                                              cnt, tlist, wrow, hmid);
  down_k<<<dim3(32, EB_), 256, 0, stream>>>(wd, sd, shwd, shsd,
                                            cnt, tlist, hmid, scr);
  combine_k<<<512, 256, 0, stream>>>(scr, out);
}